// Round 1
// baseline (16381.015 us; speedup 1.0000x reference)
//
#include <hip/hip_runtime.h>
#include <math.h>

#define B_  64
#define T_  2048
#define C_  256
#define H_  512
#define O_  256
#define NSTEP 2047

typedef __attribute__((ext_vector_type(8))) short short8x;
typedef __attribute__((ext_vector_type(4))) float f32x4;

__device__ __forceinline__ unsigned short f2bf_bits(float x){
  unsigned int u = __builtin_bit_cast(unsigned int, x);
  u = u + 0x7FFFu + ((u >> 16) & 1u);      // RNE; inputs are well-behaved (no NaN/Inf)
  return (unsigned short)(u >> 16);
}
__device__ __forceinline__ float bf2f(unsigned short h){
  unsigned int u = ((unsigned int)h) << 16;
  return __builtin_bit_cast(float, u);
}
__device__ __forceinline__ short8x pack8(float4 a, float4 b){
  short8x w;
  w[0]=(short)f2bf_bits(a.x); w[1]=(short)f2bf_bits(a.y);
  w[2]=(short)f2bf_bits(a.z); w[3]=(short)f2bf_bits(a.w);
  w[4]=(short)f2bf_bits(b.x); w[5]=(short)f2bf_bits(b.y);
  w[6]=(short)f2bf_bits(b.z); w[7]=(short)f2bf_bits(b.w);
  return w;
}
__device__ __forceinline__ f32x4 MFMA(short8x a, short8x b, f32x4 c){
  return __builtin_amdgcn_mfma_f32_16x16x32_bf16(a, b, c, 0, 0, 0);
}
__device__ __forceinline__ float softplus_f(float x){
  return (x > 20.f) ? x : log1pf(expf(x));
}
__device__ __forceinline__ float sigmoid_f(float x){
  return 1.f / (1.f + expf(-x));
}

// ---------------------------------------------------------------------------
// Init MLP: h0_pre = (softplus(softplus(x0 W0^T) W1^T)) W2^T ; store pre-retract
// bf16 row into hs[t=0] and its sum-of-squares into sumsq[0][b].
// One block per batch element; wave-per-unit dot products (coalesced weight rows).
// ---------------------------------------------------------------------------
__global__ void k_mlp(const float* __restrict__ cv,
                      const float* __restrict__ w0, const float* __restrict__ bb0,
                      const float* __restrict__ w1, const float* __restrict__ bb1,
                      const float* __restrict__ w2, const float* __restrict__ bb2,
                      unsigned short* __restrict__ hs, float* __restrict__ sumsq)
{
  const int b = blockIdx.x, tid = threadIdx.x;
  const int wave = tid >> 6, lane = tid & 63;
  __shared__ float xr[256], a0[512], a1[512], a2[512];
  __shared__ float red[4];

  xr[tid] = cv[(size_t)b * T_ * C_ + tid];      // x0 row (t = 0)
  __syncthreads();

  // layer 0: K=256
  for (int i = 0; i < 32; i++){
    float s[4];
    #pragma unroll
    for (int uu = 0; uu < 4; uu++){
      int j = wave*128 + i*4 + uu;
      const float4* wr = (const float4*)(w0 + (size_t)j * 256);
      float4 w = wr[lane];
      s[uu] = w.x*xr[lane*4+0] + w.y*xr[lane*4+1] + w.z*xr[lane*4+2] + w.w*xr[lane*4+3];
    }
    #pragma unroll
    for (int off = 32; off; off >>= 1){
      #pragma unroll
      for (int uu = 0; uu < 4; uu++) s[uu] += __shfl_xor(s[uu], off, 64);
    }
    if (lane < 4){ int j = wave*128 + i*4 + lane; a0[j] = softplus_f(s[lane] + bb0[j]); }
  }
  __syncthreads();

  // layer 1: K=512
  for (int i = 0; i < 32; i++){
    float s[4];
    #pragma unroll
    for (int uu = 0; uu < 4; uu++){
      int j = wave*128 + i*4 + uu;
      const float4* wr = (const float4*)(w1 + (size_t)j * 512);
      float4 wA = wr[lane*2], wB = wr[lane*2+1];
      int k0 = lane*8;
      s[uu] = wA.x*a0[k0]   + wA.y*a0[k0+1] + wA.z*a0[k0+2] + wA.w*a0[k0+3]
            + wB.x*a0[k0+4] + wB.y*a0[k0+5] + wB.z*a0[k0+6] + wB.w*a0[k0+7];
    }
    #pragma unroll
    for (int off = 32; off; off >>= 1){
      #pragma unroll
      for (int uu = 0; uu < 4; uu++) s[uu] += __shfl_xor(s[uu], off, 64);
    }
    if (lane < 4){ int j = wave*128 + i*4 + lane; a1[j] = softplus_f(s[lane] + bb1[j]); }
  }
  __syncthreads();

  // layer 2: K=512, no activation (pre-retract)
  for (int i = 0; i < 32; i++){
    float s[4];
    #pragma unroll
    for (int uu = 0; uu < 4; uu++){
      int j = wave*128 + i*4 + uu;
      const float4* wr = (const float4*)(w2 + (size_t)j * 512);
      float4 wA = wr[lane*2], wB = wr[lane*2+1];
      int k0 = lane*8;
      s[uu] = wA.x*a1[k0]   + wA.y*a1[k0+1] + wA.z*a1[k0+2] + wA.w*a1[k0+3]
            + wB.x*a1[k0+4] + wB.y*a1[k0+5] + wB.z*a1[k0+6] + wB.w*a1[k0+7];
    }
    #pragma unroll
    for (int off = 32; off; off >>= 1){
      #pragma unroll
      for (int uu = 0; uu < 4; uu++) s[uu] += __shfl_xor(s[uu], off, 64);
    }
    if (lane < 4){ int j = wave*128 + i*4 + lane; a2[j] = s[lane] + bb2[j]; }
  }
  __syncthreads();

  float sq = a2[tid]*a2[tid] + a2[tid+256]*a2[tid+256];
  #pragma unroll
  for (int off = 32; off; off >>= 1) sq += __shfl_xor(sq, off, 64);
  if (lane == 0) red[wave] = sq;
  __syncthreads();
  if (tid == 0) sumsq[b] = red[0] + red[1] + red[2] + red[3];
  hs[(size_t)b * 512 + tid]       = f2bf_bits(a2[tid]);
  hs[(size_t)b * 512 + tid + 256] = f2bf_bits(a2[tid + 256]);
}

// ---------------------------------------------------------------------------
// Convert w_out (256x512 fp32) to bf16 in workspace.
// ---------------------------------------------------------------------------
__global__ void k_wcvt(const float* __restrict__ w, unsigned short* __restrict__ o)
{
  int idx = blockIdx.x * 256 + threadIdx.x;
  if (idx < O_ * H_) o[idx] = f2bf_bits(w[idx]);
}

// ---------------------------------------------------------------------------
// Persistent GRU scan. 64 wgs = 4 batch-groups(16 batches) x 16 unit-slices(32 units).
// Weights live in registers as bf16 MFMA B-fragments (wave0-2: r/z/n hh-part,
// wave3: all ih-parts). Retract scale is deferred: hs holds PRE-retract h (bf16),
// sumsq[t][b] accumulated via atomicAdd; scale folded into next step's GEMM output.
// One release/acquire counter barrier per group per step.
// ---------------------------------------------------------------------------
__global__ __launch_bounds__(256, 1)
void k_scan(const float* __restrict__ cv, const float* __restrict__ w_ih,
            const float* __restrict__ w_hh, const float* __restrict__ bias,
            const float* __restrict__ b_n,
            unsigned short* __restrict__ hs, float* __restrict__ sumsq,
            unsigned* __restrict__ counters)
{
  const int wg   = blockIdx.x;      // 0..63
  const int g    = wg >> 4;         // batch group 0..3
  const int sidx = wg & 15;         // unit slice 0..15
  const int b0   = g * 16;
  const int u0   = sidx * 32;
  const int tid  = threadIdx.x;
  const int wave = tid >> 6, lane = tid & 63;
  const int lm   = lane & 15, quad = lane >> 4;

  __shared__ float accLds[12][16][16];   // slots 0..5 = hh (gate*2+nt), 6..11 = ih
  __shared__ float hpre_own[16][32];     // own slice of pre-retract h (fp32)
  __shared__ float s_lds[16];            // scale of h_{t-1} per batch
  __shared__ float bias_lds[3][32];
  __shared__ float bn_lds[32];

  if (tid < 32){
    bias_lds[0][tid] = bias[u0 + tid];
    bias_lds[1][tid] = bias[512 + u0 + tid];
    bias_lds[2][tid] = bias[1024 + u0 + tid];
    bn_lds[tid]      = b_n[u0 + tid];
  }
  for (int v = tid; v < 512; v += 256){
    int bb = v >> 5, uu = v & 31;
    hpre_own[bb][uu] = bf2f(hs[(size_t)(b0 + bb) * 512 + u0 + uu]);
  }
  if (tid < 16) s_lds[tid] = rsqrtf(sumsq[b0 + tid] + 1e-12f);

  // ---- load weight fragments into registers (bf16), once ----
  short8x wreg[48];
  if (wave < 3){
    const int gate = wave;
    #pragma unroll
    for (int nt = 0; nt < 2; nt++){
      #pragma unroll
      for (int k = 0; k < 16; k++){
        const float* p = w_hh + ((size_t)(gate*512 + u0 + nt*16 + lm)) * 512 + k*32 + quad*8;
        wreg[nt*16 + k] = pack8(*(const float4*)p, *(const float4*)(p + 4));
      }
    }
  } else {
    #pragma unroll
    for (int g2 = 0; g2 < 3; g2++){
      #pragma unroll
      for (int nt = 0; nt < 2; nt++){
        #pragma unroll
        for (int kk = 0; kk < 8; kk++){
          const float* p = w_ih + ((size_t)(g2*512 + u0 + nt*16 + lm)) * 256 + kk*32 + quad*8;
          wreg[(g2*2 + nt)*8 + kk] = pack8(*(const float4*)p, *(const float4*)(p + 4));
        }
      }
    }
  }
  __syncthreads();

  for (int t = 1; t <= NSTEP; t++){
    // ---------------- phase A: MFMAs ----------------
    if (wave < 3){
      short8x af[16];
      const size_t rowbase = ((size_t)(t-1)*64 + b0 + lm) * 512;
      #pragma unroll
      for (int k = 0; k < 16; k++)
        af[k] = *(const short8x*)(hs + rowbase + k*32 + quad*8);
      f32x4 acc0 = {0.f,0.f,0.f,0.f}, acc1 = {0.f,0.f,0.f,0.f};
      #pragma unroll
      for (int k = 0; k < 16; k++){
        acc0 = MFMA(af[k], wreg[k],      acc0);
        acc1 = MFMA(af[k], wreg[16 + k], acc1);
      }
      #pragma unroll
      for (int r = 0; r < 4; r++){
        accLds[wave*2 + 0][quad*4 + r][lm] = acc0[r];
        accLds[wave*2 + 1][quad*4 + r][lm] = acc1[r];
      }
    } else {
      short8x af[8];
      const size_t xbase = ((size_t)(b0 + lm) * T_ + t) * C_;
      #pragma unroll
      for (int kk = 0; kk < 8; kk++){
        const float* xp = cv + xbase + kk*32 + quad*8;
        af[kk] = pack8(*(const float4*)xp, *(const float4*)(xp + 4));
      }
      f32x4 acc[6];
      #pragma unroll
      for (int tt = 0; tt < 6; tt++) acc[tt] = (f32x4){0.f,0.f,0.f,0.f};
      #pragma unroll
      for (int kk = 0; kk < 8; kk++){
        #pragma unroll
        for (int tt = 0; tt < 6; tt++) acc[tt] = MFMA(af[kk], wreg[tt*8 + kk], acc[tt]);
      }
      #pragma unroll
      for (int tt = 0; tt < 6; tt++){
        #pragma unroll
        for (int r = 0; r < 4; r++) accLds[6 + tt][quad*4 + r][lm] = acc[tt][r];
      }
    }
    __syncthreads();

    // ---------------- phase B: gates (fp32) ----------------
    float sqv[2];
    #pragma unroll
    for (int hh2 = 0; hh2 < 2; hh2++){
      const int bb = (tid >> 5) + hh2*8;
      const int uu = tid & 31;
      const int nt = uu >> 4, ul = uu & 15;
      const float sp = s_lds[bb];
      float rv = accLds[6 + 0 + nt][bb][ul] + bias_lds[0][uu] + sp*accLds[0 + nt][bb][ul];
      float zv = accLds[6 + 2 + nt][bb][ul] + bias_lds[1][uu] + sp*accLds[2 + nt][bb][ul];
      float nv = accLds[6 + 4 + nt][bb][ul] + bias_lds[2][uu];
      float hn = sp*accLds[4 + nt][bb][ul];
      float r  = sigmoid_f(rv);
      float z  = sigmoid_f(zv);
      float n  = tanhf(nv + r*(hn + bn_lds[uu]));
      float hp = sp * hpre_own[bb][uu];
      float hnew = n + z*(hp - n);
      hpre_own[bb][uu] = hnew;
      hs[((size_t)t*64 + b0 + bb)*512 + u0 + uu] = f2bf_bits(hnew);
      sqv[hh2] = hnew * hnew;
    }
    #pragma unroll
    for (int off = 16; off; off >>= 1){
      sqv[0] += __shfl_down(sqv[0], off, 32);
      sqv[1] += __shfl_down(sqv[1], off, 32);
    }
    if ((lane & 31) == 0){
      const int bb = tid >> 5;
      atomicAdd(&sumsq[(size_t)t*64 + b0 + bb],     sqv[0]);
      atomicAdd(&sumsq[(size_t)t*64 + b0 + bb + 8], sqv[1]);
    }
    __syncthreads();   // all stores/atomics of this wg drained (vmcnt before barrier)

    // ---------------- barrier: 16 wgs of this group ----------------
    if (tid == 0){
      __threadfence();                       // release (agent scope)
      atomicAdd(&counters[g * 32], 1u);
      const unsigned target = 16u * (unsigned)t;
      while (__hip_atomic_load(&counters[g * 32], __ATOMIC_RELAXED,
                               __HIP_MEMORY_SCOPE_AGENT) < target){
        __builtin_amdgcn_s_sleep(1);
      }
      __threadfence();                       // acquire
    }
    __syncthreads();

    if (tid < 16){
      float v = __hip_atomic_load(&sumsq[(size_t)t*64 + b0 + tid], __ATOMIC_RELAXED,
                                  __HIP_MEMORY_SCOPE_AGENT);
      s_lds[tid] = rsqrtf(v + 1e-12f);
    }
    __syncthreads();
  }
}

// ---------------------------------------------------------------------------
// Output GEMM: y = retract(s_tb * (hs_pre @ Wout^T) + b_out), out layout (B,T,O).
// One block per time step: 64 rows x 256 cols, MFMA 16x16x32 bf16, fused retract.
// ---------------------------------------------------------------------------
__global__ __launch_bounds__(256, 2)
void k_ygemm(const unsigned short* __restrict__ hs, const float* __restrict__ sumsq,
             const unsigned short* __restrict__ wob, const float* __restrict__ b_out,
             float* __restrict__ out)
{
  const int t = blockIdx.x;
  const int tid = threadIdx.x, wave = tid >> 6, lane = tid & 63;
  const int lm = lane & 15, quad = lane >> 4;
  __shared__ float srow[64];
  __shared__ float bo[256];
  __shared__ float part[4][64];
  __shared__ float ysc[64];

  if (tid < 64) srow[tid] = rsqrtf(sumsq[(size_t)t*64 + tid] + 1e-12f);
  bo[tid] = b_out[tid];
  __syncthreads();

  f32x4 acc[4][4];
  #pragma unroll
  for (int mt = 0; mt < 4; mt++)
    #pragma unroll
    for (int nt = 0; nt < 4; nt++) acc[mt][nt] = (f32x4){0.f,0.f,0.f,0.f};

  const unsigned short* arow[4];
  const unsigned short* brow[4];
  #pragma unroll
  for (int mt = 0; mt < 4; mt++)
    arow[mt] = hs + ((size_t)t*64 + mt*16 + lm)*512 + quad*8;
  #pragma unroll
  for (int nt = 0; nt < 4; nt++)
    brow[nt] = wob + ((size_t)(wave*64 + nt*16 + lm))*512 + quad*8;

  #pragma unroll 2
  for (int k = 0; k < 16; k++){
    short8x a[4], b[4];
    #pragma unroll
    for (int mt = 0; mt < 4; mt++) a[mt] = *(const short8x*)(arow[mt] + k*32);
    #pragma unroll
    for (int nt = 0; nt < 4; nt++) b[nt] = *(const short8x*)(brow[nt] + k*32);
    #pragma unroll
    for (int mt = 0; mt < 4; mt++)
      #pragma unroll
      for (int nt = 0; nt < 4; nt++) acc[mt][nt] = MFMA(a[mt], b[nt], acc[mt][nt]);
  }

  // epilogue: y_pre = s*acc + b_out ; retract over O=256
  float loc[4][4];
  #pragma unroll
  for (int mt = 0; mt < 4; mt++)
    #pragma unroll
    for (int r = 0; r < 4; r++) loc[mt][r] = 0.f;
  #pragma unroll
  for (int mt = 0; mt < 4; mt++){
    #pragma unroll
    for (int nt = 0; nt < 4; nt++){
      f32x4 v = acc[mt][nt];
      #pragma unroll
      for (int r = 0; r < 4; r++){
        int row = mt*16 + quad*4 + r;
        float y = srow[row]*v[r] + bo[wave*64 + nt*16 + lm];
        v[r] = y;
        loc[mt][r] += y*y;
      }
      acc[mt][nt] = v;
    }
  }
  #pragma unroll
  for (int off = 8; off; off >>= 1){
    #pragma unroll
    for (int mt = 0; mt < 4; mt++)
      #pragma unroll
      for (int r = 0; r < 4; r++) loc[mt][r] += __shfl_xor(loc[mt][r], off, 16);
  }
  if (lm == 0){
    #pragma unroll
    for (int mt = 0; mt < 4; mt++)
      #pragma unroll
      for (int r = 0; r < 4; r++) part[wave][mt*16 + quad*4 + r] = loc[mt][r];
  }
  __syncthreads();
  if (tid < 64) ysc[tid] = rsqrtf(part[0][tid] + part[1][tid] + part[2][tid] + part[3][tid] + 1e-12f);
  __syncthreads();

  #pragma unroll
  for (int mt = 0; mt < 4; mt++){
    #pragma unroll
    for (int nt = 0; nt < 4; nt++){
      #pragma unroll
      for (int r = 0; r < 4; r++){
        int row = mt*16 + quad*4 + r;                 // batch b
        int o   = wave*64 + nt*16 + lm;
        out[((size_t)row * T_ + t) * O_ + o] = acc[mt][nt][r] * ysc[row];
      }
    }
  }
}

// ---------------------------------------------------------------------------
extern "C" void kernel_launch(void* const* d_in, const int* in_sizes, int n_in,
                              void* d_out, int out_size, void* d_ws, size_t ws_size,
                              hipStream_t stream)
{
  (void)in_sizes; (void)n_in; (void)out_size;
  const float* cv   = (const float*)d_in[0];
  const float* w0   = (const float*)d_in[1];
  const float* b0v  = (const float*)d_in[2];
  const float* w1   = (const float*)d_in[3];
  const float* b1v  = (const float*)d_in[4];
  const float* w2   = (const float*)d_in[5];
  const float* b2v  = (const float*)d_in[6];
  const float* wih  = (const float*)d_in[7];
  const float* whh  = (const float*)d_in[8];
  const float* bg   = (const float*)d_in[9];
  const float* bn   = (const float*)d_in[10];
  const float* wout = (const float*)d_in[11];
  const float* bout = (const float*)d_in[12];
  float* out = (float*)d_out;

  // workspace layout
  const size_t HS_BYTES = (size_t)T_ * B_ * H_ * 2;        // 134217728  pre-retract h, bf16
  const size_t SS_BYTES = (size_t)T_ * B_ * 4;             // 524288     sumsq per (t,b)
  const size_t OFF_SS   = HS_BYTES;
  const size_t OFF_CNT  = OFF_SS + SS_BYTES;               // 4 counters, 128B stride
  const size_t OFF_WOB  = OFF_CNT + 512;
  const size_t NEED     = OFF_WOB + (size_t)O_ * H_ * 2;
  if (ws_size < NEED) return;

  unsigned short* hs    = (unsigned short*)d_ws;
  float*          sumsq = (float*)((char*)d_ws + OFF_SS);
  unsigned*       cnt   = (unsigned*)((char*)d_ws + OFF_CNT);
  unsigned short* wob   = (unsigned short*)((char*)d_ws + OFF_WOB);

  hipMemsetAsync((char*)d_ws + OFF_SS, 0, SS_BYTES + 512, stream);
  hipLaunchKernelGGL(k_mlp,   dim3(64),   dim3(256), 0, stream,
                     cv, w0, b0v, w1, b1v, w2, b2v, hs, sumsq);
  hipLaunchKernelGGL(k_wcvt,  dim3(512),  dim3(256), 0, stream, wout, wob);
  hipLaunchKernelGGL(k_scan,  dim3(64),   dim3(256), 0, stream,
                     cv, wih, whh, bg, bn, hs, sumsq, cnt);
  hipLaunchKernelGGL(k_ygemm, dim3(2048), dim3(256), 0, stream,
                     hs, sumsq, wob, bout, out);
}

// Round 2
// 7938.682 us; speedup vs baseline: 2.0634x; 2.0634x over previous
//
#include <hip/hip_runtime.h>
#include <math.h>

#define B_  64
#define T_  2048
#define C_  256
#define H_  512
#define O_  256
#define NSTEP 2047

typedef __attribute__((ext_vector_type(8))) short short8x;
typedef __attribute__((ext_vector_type(4))) float f32x4;

__device__ __forceinline__ unsigned short f2bf_bits(float x){
  unsigned int u = __builtin_bit_cast(unsigned int, x);
  u = u + 0x7FFFu + ((u >> 16) & 1u);      // RNE
  return (unsigned short)(u >> 16);
}
__device__ __forceinline__ float bf2f(unsigned short h){
  unsigned int u = ((unsigned int)h) << 16;
  return __builtin_bit_cast(float, u);
}
__device__ __forceinline__ short8x pack8(float4 a, float4 b){
  short8x w;
  w[0]=(short)f2bf_bits(a.x); w[1]=(short)f2bf_bits(a.y);
  w[2]=(short)f2bf_bits(a.z); w[3]=(short)f2bf_bits(a.w);
  w[4]=(short)f2bf_bits(b.x); w[5]=(short)f2bf_bits(b.y);
  w[6]=(short)f2bf_bits(b.z); w[7]=(short)f2bf_bits(b.w);
  return w;
}
__device__ __forceinline__ f32x4 MFMA(short8x a, short8x b, f32x4 c){
  return __builtin_amdgcn_mfma_f32_16x16x32_bf16(a, b, c, 0, 0, 0);
}
__device__ __forceinline__ float softplus_f(float x){
  return (x > 20.f) ? x : log1pf(expf(x));
}
// fast device math: native v_exp_f32 (2^x) + v_rcp_f32
__device__ __forceinline__ float fast_exp2(float x){ return __builtin_amdgcn_exp2f(x); }
__device__ __forceinline__ float fast_rcp(float x){ return __builtin_amdgcn_rcpf(x); }
__device__ __forceinline__ float sigmoid_f(float x){
  return fast_rcp(1.f + fast_exp2(-1.44269504f * x));
}
__device__ __forceinline__ float tanh_f(float x){
  // tanh(x) = 1 - 2/(exp2(2x*log2e)+1); saturates correctly at +-inf
  return 1.f - 2.f * fast_rcp(1.f + fast_exp2(2.88539008f * x));
}

// device-scope (agent) accesses: write-through to coherence point, bypass stale L1/L2.
__device__ __forceinline__ void st_agent_u32(unsigned* p, unsigned v){
  __hip_atomic_store(p, v, __ATOMIC_RELAXED, __HIP_MEMORY_SCOPE_AGENT);
}
__device__ __forceinline__ void st_agent_u16(unsigned short* p, unsigned short v){
  __hip_atomic_store(p, v, __ATOMIC_RELAXED, __HIP_MEMORY_SCOPE_AGENT);
}
__device__ __forceinline__ void st_agent_f32(float* p, float v){
  __hip_atomic_store(p, v, __ATOMIC_RELAXED, __HIP_MEMORY_SCOPE_AGENT);
}
__device__ __forceinline__ unsigned ld_agent_u32(unsigned* p){
  return __hip_atomic_load(p, __ATOMIC_RELAXED, __HIP_MEMORY_SCOPE_AGENT);
}
__device__ __forceinline__ float ld_agent_f32(float* p){
  return __hip_atomic_load(p, __ATOMIC_RELAXED, __HIP_MEMORY_SCOPE_AGENT);
}

// hs layout: [t][g(4)][slice(16)][bb(16)][u(32)] bf16  -> slice block = 1 KiB, line-exclusive per wg.
// index(t,g,s,bb,u) = ((t*4+g)*8192) + s*512 + bb*32 + u   (in shorts)

// ---------------------------------------------------------------------------
// Init MLP -> hs[t=0] (pre-retract bf16, new layout) + partials parity0.
// ---------------------------------------------------------------------------
__global__ void k_mlp(const float* __restrict__ cv,
                      const float* __restrict__ w0, const float* __restrict__ bb0,
                      const float* __restrict__ w1, const float* __restrict__ bb1,
                      const float* __restrict__ w2, const float* __restrict__ bb2,
                      unsigned short* __restrict__ hs, float* __restrict__ partials)
{
  const int b = blockIdx.x, tid = threadIdx.x;
  const int wave = tid >> 6, lane = tid & 63;
  __shared__ float xr[256], a0[512], a1[512], a2[512];
  __shared__ float red[4];

  xr[tid] = cv[(size_t)b * T_ * C_ + tid];      // x0 row (t = 0)
  __syncthreads();

  for (int i = 0; i < 32; i++){
    float s[4];
    #pragma unroll
    for (int uu = 0; uu < 4; uu++){
      int j = wave*128 + i*4 + uu;
      const float4* wr = (const float4*)(w0 + (size_t)j * 256);
      float4 w = wr[lane];
      s[uu] = w.x*xr[lane*4+0] + w.y*xr[lane*4+1] + w.z*xr[lane*4+2] + w.w*xr[lane*4+3];
    }
    #pragma unroll
    for (int off = 32; off; off >>= 1){
      #pragma unroll
      for (int uu = 0; uu < 4; uu++) s[uu] += __shfl_xor(s[uu], off, 64);
    }
    if (lane < 4){ int j = wave*128 + i*4 + lane; a0[j] = softplus_f(s[lane] + bb0[j]); }
  }
  __syncthreads();

  for (int i = 0; i < 32; i++){
    float s[4];
    #pragma unroll
    for (int uu = 0; uu < 4; uu++){
      int j = wave*128 + i*4 + uu;
      const float4* wr = (const float4*)(w1 + (size_t)j * 512);
      float4 wA = wr[lane*2], wB = wr[lane*2+1];
      int k0 = lane*8;
      s[uu] = wA.x*a0[k0]   + wA.y*a0[k0+1] + wA.z*a0[k0+2] + wA.w*a0[k0+3]
            + wB.x*a0[k0+4] + wB.y*a0[k0+5] + wB.z*a0[k0+6] + wB.w*a0[k0+7];
    }
    #pragma unroll
    for (int off = 32; off; off >>= 1){
      #pragma unroll
      for (int uu = 0; uu < 4; uu++) s[uu] += __shfl_xor(s[uu], off, 64);
    }
    if (lane < 4){ int j = wave*128 + i*4 + lane; a1[j] = softplus_f(s[lane] + bb1[j]); }
  }
  __syncthreads();

  for (int i = 0; i < 32; i++){
    float s[4];
    #pragma unroll
    for (int uu = 0; uu < 4; uu++){
      int j = wave*128 + i*4 + uu;
      const float4* wr = (const float4*)(w2 + (size_t)j * 512);
      float4 wA = wr[lane*2], wB = wr[lane*2+1];
      int k0 = lane*8;
      s[uu] = wA.x*a1[k0]   + wA.y*a1[k0+1] + wA.z*a1[k0+2] + wA.w*a1[k0+3]
            + wB.x*a1[k0+4] + wB.y*a1[k0+5] + wB.z*a1[k0+6] + wB.w*a1[k0+7];
    }
    #pragma unroll
    for (int off = 32; off; off >>= 1){
      #pragma unroll
      for (int uu = 0; uu < 4; uu++) s[uu] += __shfl_xor(s[uu], off, 64);
    }
    if (lane < 4){ int j = wave*128 + i*4 + lane; a2[j] = s[lane] + bb2[j]; }
  }
  __syncthreads();

  float sq = a2[tid]*a2[tid] + a2[tid+256]*a2[tid+256];
  #pragma unroll
  for (int off = 32; off; off >>= 1) sq += __shfl_xor(sq, off, 64);
  if (lane == 0) red[wave] = sq;
  __syncthreads();

  const int g = b >> 4, bb = b & 15;
  // partials layout: [parity(2)][g(4)][slice(16)][32 floats, first 16 used]
  if (tid == 0)               partials[(size_t)g*512 + 0*32  + bb] = red[0]+red[1]+red[2]+red[3];
  if (tid >= 1 && tid < 16)   partials[(size_t)g*512 + tid*32 + bb] = 0.f;

  // hs[0] in new layout
  {
    int u = tid;
    hs[(size_t)g*8192 + (u>>5)*512 + bb*32 + (u&31)] = f2bf_bits(a2[u]);
    u = tid + 256;
    hs[(size_t)g*8192 + (u>>5)*512 + bb*32 + (u&31)] = f2bf_bits(a2[u]);
  }
}

// ---------------------------------------------------------------------------
__global__ void k_wcvt(const float* __restrict__ w, unsigned short* __restrict__ o)
{
  int idx = blockIdx.x * 256 + threadIdx.x;
  if (idx < O_ * H_) o[idx] = f2bf_bits(w[idx]);
}

// ---------------------------------------------------------------------------
// Persistent GRU scan, fence-free barrier (sc1 stores + flag publish + poll).
// 64 wgs = 4 batch-groups(16 batches) x 16 unit-slices(32 units).
// ---------------------------------------------------------------------------
__global__ __launch_bounds__(256, 1)
void k_scan(const float* __restrict__ cv, const float* __restrict__ w_ih,
            const float* __restrict__ w_hh, const float* __restrict__ bias,
            const float* __restrict__ b_n,
            unsigned short* __restrict__ hs, float* __restrict__ sumsq,
            unsigned* __restrict__ flags, float* __restrict__ partials)
{
  const int wg   = blockIdx.x;
  const int g    = wg >> 4;         // batch group 0..3
  const int sidx = wg & 15;         // unit slice 0..15
  const int b0   = g * 16;
  const int u0   = sidx * 32;
  const int tid  = threadIdx.x;
  const int wave = tid >> 6, lane = tid & 63;
  const int lm   = lane & 15, quad = lane >> 4;
  const int gb   = tid >> 5;        // 0..7 (batch row within group, first half)
  const int uu   = tid & 31;        // unit within slice

  __shared__ float accLds[12][16][16];   // 0..5 hh (gate*2+nt), 6..11 ih
  __shared__ float s_lds[16];            // rsqrt(sumsq(h_{t-1})) per batch
  __shared__ float bias_lds[3][32];
  __shared__ float bn_lds[32];

  if (tid < 32){
    bias_lds[0][tid] = bias[u0 + tid];
    bias_lds[1][tid] = bias[512 + u0 + tid];
    bias_lds[2][tid] = bias[1024 + u0 + tid];
    bn_lds[tid]      = b_n[u0 + tid];
  }
  // own pre-retract h (fp32) in registers
  float hp0 = bf2f(hs[(size_t)g*8192 + sidx*512 + gb*32 + uu]);
  float hp1 = bf2f(hs[(size_t)g*8192 + sidx*512 + (gb+8)*32 + uu]);

  // ---- weight fragments in registers (bf16), loaded once ----
  short8x wreg[48];
  if (wave < 3){
    const int gate = wave;
    #pragma unroll
    for (int nt = 0; nt < 2; nt++){
      #pragma unroll
      for (int k = 0; k < 16; k++){
        const float* p = w_hh + ((size_t)(gate*512 + u0 + nt*16 + lm)) * 512 + k*32 + quad*8;
        wreg[nt*16 + k] = pack8(*(const float4*)p, *(const float4*)(p + 4));
      }
    }
  } else {
    #pragma unroll
    for (int g2 = 0; g2 < 3; g2++){
      #pragma unroll
      for (int nt = 0; nt < 2; nt++){
        #pragma unroll
        for (int kk = 0; kk < 8; kk++){
          const float* p = w_ih + ((size_t)(g2*512 + u0 + nt*16 + lm)) * 256 + kk*32 + quad*8;
          wreg[(g2*2 + nt)*8 + kk] = pack8(*(const float4*)p, *(const float4*)(p + 4));
        }
      }
    }
  }
  __syncthreads();

  unsigned* gflags = flags + g*32;

  for (int t = 1; t <= NSTEP; t++){
    const unsigned tgt = (unsigned)(t - 1);
    // publish h_{t-1} completion (stores drained by __syncthreads of prev iter)
    if (tid == 0) st_agent_u32(&gflags[sidx], tgt);

    if (wave < 3){
      // ---- wait for all slices' h_{t-1}, then hh-GEMM ----
      for (;;){
        unsigned f = (lane < 16) ? ld_agent_u32(&gflags[lane]) : tgt;
        if (__all((int)(f >= tgt))) break;
      }
      asm volatile("" ::: "memory");
      const unsigned short* base = hs + ((size_t)(t-1)*4 + g)*8192 + lm*32 + quad*8;
      short8x af[16];
      #pragma unroll
      for (int k = 0; k < 16; k++)
        af[k] = *(const short8x*)(base + (size_t)k*512);
      f32x4 acc0 = {0.f,0.f,0.f,0.f}, acc1 = {0.f,0.f,0.f,0.f};
      #pragma unroll
      for (int k = 0; k < 16; k++){
        acc0 = MFMA(af[k], wreg[k],      acc0);
        acc1 = MFMA(af[k], wreg[16 + k], acc1);
      }
      #pragma unroll
      for (int r = 0; r < 4; r++){
        accLds[wave*2 + 0][quad*4 + r][lm] = acc0[r];
        accLds[wave*2 + 1][quad*4 + r][lm] = acc1[r];
      }
    } else {
      // ---- ig part first (independent of barrier) ----
      short8x af[8];
      const size_t xbase = ((size_t)(b0 + lm) * T_ + t) * C_;
      #pragma unroll
      for (int kk = 0; kk < 8; kk++){
        const float* xp = cv + xbase + kk*32 + quad*8;
        af[kk] = pack8(*(const float4*)xp, *(const float4*)(xp + 4));
      }
      f32x4 acc[6];
      #pragma unroll
      for (int tt = 0; tt < 6; tt++) acc[tt] = (f32x4){0.f,0.f,0.f,0.f};
      #pragma unroll
      for (int kk = 0; kk < 8; kk++){
        #pragma unroll
        for (int tt = 0; tt < 6; tt++) acc[tt] = MFMA(af[kk], wreg[tt*8 + kk], acc[tt]);
      }
      #pragma unroll
      for (int tt = 0; tt < 6; tt++){
        #pragma unroll
        for (int r = 0; r < 4; r++) accLds[6 + tt][quad*4 + r][lm] = acc[tt][r];
      }
      // ---- then wait + reduce sumsq partials of h_{t-1} ----
      for (;;){
        unsigned f = (lane < 16) ? ld_agent_u32(&gflags[lane]) : tgt;
        if (__all((int)(f >= tgt))) break;
      }
      asm volatile("" ::: "memory");
      if (lane < 16){
        float* pp = partials + (size_t)((t-1)&1)*2048 + g*512 + lane;
        float v = 0.f;
        #pragma unroll
        for (int s = 0; s < 16; s++) v += ld_agent_f32(pp + s*32);
        if (sidx == 0) sumsq[(size_t)(t-1)*64 + b0 + lane] = v;
        s_lds[lane] = rsqrtf(v + 1e-12f);
      }
    }
    __syncthreads();

    // ---------------- gate phase (all 256 threads, 2 elems each) ----------------
    const int nt = uu >> 4, ul = uu & 15;
    float sq0, sq1;
    {
      const float sp = s_lds[gb];
      float rv = accLds[6 + 0 + nt][gb][ul] + bias_lds[0][uu] + sp*accLds[0 + nt][gb][ul];
      float zv = accLds[6 + 2 + nt][gb][ul] + bias_lds[1][uu] + sp*accLds[2 + nt][gb][ul];
      float nv = accLds[6 + 4 + nt][gb][ul] + bias_lds[2][uu];
      float hn = sp*accLds[4 + nt][gb][ul];
      float r  = sigmoid_f(rv);
      float z  = sigmoid_f(zv);
      float n  = tanh_f(nv + r*(hn + bn_lds[uu]));
      float hp = sp * hp0;
      float hnew = n + z*(hp - n);
      hp0 = hnew;
      st_agent_u16(hs + ((size_t)t*4 + g)*8192 + sidx*512 + gb*32 + uu, f2bf_bits(hnew));
      sq0 = hnew * hnew;
    }
    {
      const float sp = s_lds[gb + 8];
      float rv = accLds[6 + 0 + nt][gb+8][ul] + bias_lds[0][uu] + sp*accLds[0 + nt][gb+8][ul];
      float zv = accLds[6 + 2 + nt][gb+8][ul] + bias_lds[1][uu] + sp*accLds[2 + nt][gb+8][ul];
      float nv = accLds[6 + 4 + nt][gb+8][ul] + bias_lds[2][uu];
      float hn = sp*accLds[4 + nt][gb+8][ul];
      float r  = sigmoid_f(rv);
      float z  = sigmoid_f(zv);
      float n  = tanh_f(nv + r*(hn + bn_lds[uu]));
      float hp = sp * hp1;
      float hnew = n + z*(hp - n);
      hp1 = hnew;
      st_agent_u16(hs + ((size_t)t*4 + g)*8192 + sidx*512 + (gb+8)*32 + uu, f2bf_bits(hnew));
      sq1 = hnew * hnew;
    }
    #pragma unroll
    for (int off = 16; off; off >>= 1){
      sq0 += __shfl_down(sq0, off, 32);
      sq1 += __shfl_down(sq1, off, 32);
    }
    if ((lane & 31) == 0){
      float* pb = partials + (size_t)(t&1)*2048 + g*512 + sidx*32;
      st_agent_f32(pb + gb,     sq0);
      st_agent_f32(pb + gb + 8, sq1);
    }
    __syncthreads();   // drains vmcnt: all sc1 stores complete before flag publish
  }

  // epilogue: publish final step, write sumsq for t = NSTEP
  if (tid == 0) st_agent_u32(&gflags[sidx], (unsigned)NSTEP);
  if (wave == 3 && sidx == 0){
    const unsigned tgt = (unsigned)NSTEP;
    for (;;){
      unsigned f = (lane < 16) ? ld_agent_u32(&gflags[lane]) : tgt;
      if (__all((int)(f >= tgt))) break;
    }
    asm volatile("" ::: "memory");
    if (lane < 16){
      float* pp = partials + (size_t)(NSTEP&1)*2048 + g*512 + lane;
      float v = 0.f;
      #pragma unroll
      for (int s = 0; s < 16; s++) v += ld_agent_f32(pp + s*32);
      sumsq[(size_t)NSTEP*64 + b0 + lane] = v;
    }
  }
}

// ---------------------------------------------------------------------------
// Output GEMM with fused retract. hs layout [t][g][slice][bb][u].
// ---------------------------------------------------------------------------
__global__ __launch_bounds__(256, 2)
void k_ygemm(const unsigned short* __restrict__ hs, const float* __restrict__ sumsq,
             const unsigned short* __restrict__ wob, const float* __restrict__ b_out,
             float* __restrict__ out)
{
  const int t = blockIdx.x;
  const int tid = threadIdx.x, wave = tid >> 6, lane = tid & 63;
  const int lm = lane & 15, quad = lane >> 4;
  __shared__ float srow[64];
  __shared__ float bo[256];
  __shared__ float part[4][64];
  __shared__ float ysc[64];

  if (tid < 64) srow[tid] = rsqrtf(sumsq[(size_t)t*64 + tid] + 1e-12f);
  bo[tid] = b_out[tid];
  __syncthreads();

  f32x4 acc[4][4];
  #pragma unroll
  for (int mt = 0; mt < 4; mt++)
    #pragma unroll
    for (int nt = 0; nt < 4; nt++) acc[mt][nt] = (f32x4){0.f,0.f,0.f,0.f};

  const unsigned short* arow[4];
  const unsigned short* brow[4];
  #pragma unroll
  for (int mt = 0; mt < 4; mt++)   // batch row b = mt*16+lm -> g=mt, bb=lm, slice k
    arow[mt] = hs + ((size_t)t*4 + mt)*8192 + lm*32 + quad*8;
  #pragma unroll
  for (int nt = 0; nt < 4; nt++)
    brow[nt] = wob + ((size_t)(wave*64 + nt*16 + lm))*512 + quad*8;

  #pragma unroll 2
  for (int k = 0; k < 16; k++){
    short8x a[4], b[4];
    #pragma unroll
    for (int mt = 0; mt < 4; mt++) a[mt] = *(const short8x*)(arow[mt] + (size_t)k*512);
    #pragma unroll
    for (int nt = 0; nt < 4; nt++) b[nt] = *(const short8x*)(brow[nt] + k*32);
    #pragma unroll
    for (int mt = 0; mt < 4; mt++)
      #pragma unroll
      for (int nt = 0; nt < 4; nt++) acc[mt][nt] = MFMA(a[mt], b[nt], acc[mt][nt]);
  }

  float loc[4][4];
  #pragma unroll
  for (int mt = 0; mt < 4; mt++)
    #pragma unroll
    for (int r = 0; r < 4; r++) loc[mt][r] = 0.f;
  #pragma unroll
  for (int mt = 0; mt < 4; mt++){
    #pragma unroll
    for (int nt = 0; nt < 4; nt++){
      f32x4 v = acc[mt][nt];
      #pragma unroll
      for (int r = 0; r < 4; r++){
        int row = mt*16 + quad*4 + r;
        float y = srow[row]*v[r] + bo[wave*64 + nt*16 + lm];
        v[r] = y;
        loc[mt][r] += y*y;
      }
      acc[mt][nt] = v;
    }
  }
  #pragma unroll
  for (int off = 8; off; off >>= 1){
    #pragma unroll
    for (int mt = 0; mt < 4; mt++)
      #pragma unroll
      for (int r = 0; r < 4; r++) loc[mt][r] += __shfl_xor(loc[mt][r], off, 16);
  }
  if (lm == 0){
    #pragma unroll
    for (int mt = 0; mt < 4; mt++)
      #pragma unroll
      for (int r = 0; r < 4; r++) part[wave][mt*16 + quad*4 + r] = loc[mt][r];
  }
  __syncthreads();
  if (tid < 64) ysc[tid] = rsqrtf(part[0][tid] + part[1][tid] + part[2][tid] + part[3][tid] + 1e-12f);
  __syncthreads();

  #pragma unroll
  for (int mt = 0; mt < 4; mt++){
    #pragma unroll
    for (int nt = 0; nt < 4; nt++){
      #pragma unroll
      for (int r = 0; r < 4; r++){
        int row = mt*16 + quad*4 + r;
        int o   = wave*64 + nt*16 + lm;
        out[((size_t)row * T_ + t) * O_ + o] = acc[mt][nt][r] * ysc[row];
      }
    }
  }
}

// ---------------------------------------------------------------------------
extern "C" void kernel_launch(void* const* d_in, const int* in_sizes, int n_in,
                              void* d_out, int out_size, void* d_ws, size_t ws_size,
                              hipStream_t stream)
{
  (void)in_sizes; (void)n_in; (void)out_size;
  const float* cv   = (const float*)d_in[0];
  const float* w0   = (const float*)d_in[1];
  const float* b0v  = (const float*)d_in[2];
  const float* w1   = (const float*)d_in[3];
  const float* b1v  = (const float*)d_in[4];
  const float* w2   = (const float*)d_in[5];
  const float* b2v  = (const float*)d_in[6];
  const float* wih  = (const float*)d_in[7];
  const float* whh  = (const float*)d_in[8];
  const float* bg   = (const float*)d_in[9];
  const float* bn   = (const float*)d_in[10];
  const float* wout = (const float*)d_in[11];
  const float* bout = (const float*)d_in[12];
  float* out = (float*)d_out;

  // workspace layout
  const size_t HS_BYTES  = (size_t)T_ * B_ * H_ * 2;        // 134217728, bf16 pre-retract h
  const size_t SS_BYTES  = (size_t)T_ * B_ * 4;             // 524288, sumsq totals
  const size_t OFF_SS    = HS_BYTES;
  const size_t OFF_FLG   = OFF_SS + SS_BYTES;               // 4 groups x 32 dwords = 512 B
  const size_t OFF_PART  = OFF_FLG + 512;                   // 2 x 4 x 16 x 32 floats = 16 KiB
  const size_t OFF_WOB   = OFF_PART + 16384;
  const size_t NEED      = OFF_WOB + (size_t)O_ * H_ * 2;
  if (ws_size < NEED) return;

  unsigned short* hs    = (unsigned short*)d_ws;
  float*          sumsq = (float*)((char*)d_ws + OFF_SS);
  unsigned*       flg   = (unsigned*)((char*)d_ws + OFF_FLG);
  float*          par   = (float*)((char*)d_ws + OFF_PART);
  unsigned short* wob   = (unsigned short*)((char*)d_ws + OFF_WOB);

  hipMemsetAsync((char*)d_ws + OFF_FLG, 0, 512, stream);
  hipLaunchKernelGGL(k_mlp,   dim3(64),   dim3(256), 0, stream,
                     cv, w0, b0v, w1, b1v, w2, b2v, hs, par);
  hipLaunchKernelGGL(k_wcvt,  dim3(512),  dim3(256), 0, stream, wout, wob);
  hipLaunchKernelGGL(k_scan,  dim3(64),   dim3(256), 0, stream,
                     cv, wih, whh, bg, bn, hs, sumsq, flg, par);
  hipLaunchKernelGGL(k_ygemm, dim3(2048), dim3(256), 0, stream,
                     hs, sumsq, wob, bout, out);
}